// Round 6
// baseline (126.288 us; speedup 1.0000x reference)
//
#include <hip/hip_runtime.h>

#define Q21 (1u<<21)
#define THREADS 512
#define BLOCKS 1024   // 1024*512 threads * 4 quads = 2^21 quads

// ws layout: [0, 1024*16*8) double part[BLOCKS][16] — per-block Gram partials.
//
// Math chain (each step verified on HW, absmax 0 at every stage r1-r5):
//  E = <psi_f|Z_22|psi_f>/||psi||^2 collapses to a 4x4 Hermitian observable C
//  on bits {22,21} (r5). New this round: by linearity,
//     sum_v q(v)^dag C q(v) = Tr(C * G),   G = sum_v q(v) q(v)^dag,
//     ||psi||^2 = Tr(G),
//  with q(v) = (psi[v], psi[v+2^21], psi[v+2^22], psi[v+3*2^21]), v < 2^21.
//  So the data pass (gramk) is theta-independent: accumulate G (4 norms +
//  6 complex off-diagonals = 16 reals), per-block partials to ws, no atomics.
//  fink reduces partials, builds C in fp64 (verbatim r5-verified code), and
//  emits E = Tr(C G)/Tr(G).
// Pair order p=0..5: (m,n) = (0,1),(0,2),(0,3),(1,2),(1,3),(2,3);
//  G[4+2p]=sum Re(conj(q_m) q_n), G[5+2p]=sum Im(conj(q_m) q_n).

struct cd { double r, i; };
__device__ __forceinline__ cd cmul(cd a, cd b){ return {a.r*b.r - a.i*b.i, a.r*b.i + a.i*b.r}; }
__device__ __forceinline__ cd cjg(cd a){ return {a.r, -a.i}; }
__device__ __forceinline__ cd cadd(cd a, cd b){ return {a.r+b.r, a.i+b.i}; }

// Gram streaming pass: 64 MB read, 128 KB written, no atomics, no init needed.
__global__ __launch_bounds__(THREADS)
void gramk(const float* __restrict__ sr, const float* __restrict__ si,
           double* __restrict__ part){
  int gt = blockIdx.x*THREADS + threadIdx.x;
  int v  = gt<<2;
  float rr[4][4], ii[4][4];
  *(float4*)&rr[0][0] = *(const float4*)(sr+v);
  *(float4*)&rr[1][0] = *(const float4*)(sr+v+Q21);
  *(float4*)&rr[2][0] = *(const float4*)(sr+v+2*Q21);
  *(float4*)&rr[3][0] = *(const float4*)(sr+v+3*Q21);
  *(float4*)&ii[0][0] = *(const float4*)(si+v);
  *(float4*)&ii[1][0] = *(const float4*)(si+v+Q21);
  *(float4*)&ii[2][0] = *(const float4*)(si+v+2*Q21);
  *(float4*)&ii[3][0] = *(const float4*)(si+v+3*Q21);
  float acc[16];
  #pragma unroll
  for(int k=0;k<16;++k) acc[k]=0.f;
  const int pm[6]={0,0,0,1,1,2}, pn[6]={1,2,3,2,3,3};
  #pragma unroll
  for(int e=0;e<4;++e){
    float qr[4]={rr[0][e],rr[1][e],rr[2][e],rr[3][e]};
    float qi[4]={ii[0][e],ii[1][e],ii[2][e],ii[3][e]};
    #pragma unroll
    for(int m=0;m<4;++m) acc[m] += qr[m]*qr[m] + qi[m]*qi[m];
    #pragma unroll
    for(int p=0;p<6;++p){
      int m=pm[p], n=pn[p];
      acc[4+2*p] += qr[m]*qr[n] + qi[m]*qi[n];   // Re(conj(q_m) q_n)
      acc[5+2*p] += qr[m]*qi[n] - qi[m]*qr[n];   // Im(conj(q_m) q_n)
    }
  }
  double d[16];
  #pragma unroll
  for(int k=0;k<16;++k) d[k]=(double)acc[k];
  #pragma unroll
  for(int off=32;off>0;off>>=1){
    #pragma unroll
    for(int k=0;k<16;++k) d[k] += __shfl_down(d[k], off);
  }
  __shared__ double red[8][16];
  int w = threadIdx.x>>6;
  if((threadIdx.x&63)==0){
    #pragma unroll
    for(int k=0;k<16;++k) red[w][k]=d[k];
  }
  __syncthreads();
  if(threadIdx.x<16){
    double s=0;
    #pragma unroll
    for(int i=0;i<8;++i) s += red[i][threadIdx.x];
    part[blockIdx.x*16 + threadIdx.x] = s;
  }
}

// Final: reduce per-block Gram partials, build C (fp64, r5-verified code),
// output E = Tr(C G)/Tr(G). One block, 256 threads.
__global__ void fink(const float* __restrict__ thetas,
                     const double* __restrict__ part, float* __restrict__ out){
  __shared__ double red[16][17];
  __shared__ double G[16];
  int t = threadIdx.x;                 // 256
  int comp = t&15, grp = t>>4;         // 16 comps x 16 groups
  double s = 0.0;
  for(int b=grp; b<BLOCKS; b+=16) s += part[b*16 + comp];
  red[comp][grp] = s;
  __syncthreads();
  if(t<16){
    double g=0;
    #pragma unroll
    for(int i=0;i<16;++i) g += red[t][i];
    G[t]=g;
  }
  __syncthreads();
  if(t==0){
    // ---- C construction: verbatim from r5 initk (HW-verified, absmax 0) ----
    double a0=0.5*(double)thetas[0], b0=0.5*(double)thetas[1];   // qubit0 L0
    double a1=0.5*(double)thetas[2], b1=0.5*(double)thetas[3];   // qubit1 L0
    double ax=0.5*(double)thetas[46], bx=0.5*(double)thetas[47]; // qubit0 L1
    cd U0[2][2], U1[2][2], V[2][2];
    {
      double ca=cos(a0), sa=sin(a0), cb=cos(b0), sb=sin(b0);
      U0[0][0]={ca*cb,-ca*sb}; U0[0][1]={-sa*cb, sa*sb};
      U0[1][0]={sa*cb, sa*sb}; U0[1][1]={ ca*cb, ca*sb};
    }
    {
      double ca=cos(a1), sa=sin(a1), cb=cos(b1), sb=sin(b1);
      U1[0][0]={ca*cb,-ca*sb}; U1[0][1]={-sa*cb, sa*sb};
      U1[1][0]={sa*cb, sa*sb}; U1[1][1]={ ca*cb, ca*sb};
    }
    {
      double ca=cos(ax), sa=sin(ax), cb=cos(bx), sb=sin(bx);
      V[0][0]={cb*ca, sb*sa}; V[0][1]={-sb*ca,-cb*sa};
      V[1][0]={sb*ca,-cb*sa}; V[1][1]={ cb*ca,-sb*sa};
    }
    double aM = (V[0][0].r*V[0][0].r+V[0][0].i*V[0][0].i)
              - (V[1][0].r*V[1][0].r+V[1][0].i*V[1][0].i);
    cd O01 = cadd(cmul(cjg(V[0][0]),V[0][1]), {-cmul(cjg(V[1][0]),V[1][1]).r,
                                               -cmul(cjg(V[1][0]),V[1][1]).i});
    cd B[4][4];
    for(int j=0;j<4;++j) for(int k=0;k<4;++k) B[j][k]={0,0};
    B[0][0]={aM,0}; B[1][1]={aM,0}; B[2][2]={-aM,0}; B[3][3]={-aM,0};
    B[0][3]=O01; B[3][0]=cjg(O01); B[1][2]=O01; B[2][1]=cjg(O01);
    cd W[4][4];
    for(int m=0;m<4;++m) for(int n=0;n<4;++n)
      W[m][n] = cmul(U0[m>>1][n>>1], U1[m&1][n&1]);
    cd C[4][4];
    for(int m=0;m<4;++m) for(int n=0;n<4;++n){
      cd sacc={0,0};
      for(int j=0;j<4;++j) for(int k=0;k<4;++k)
        sacc = cadd(sacc, cmul(cmul(cjg(W[j][m]), B[j][k]), W[k][n]));
      C[m][n]=sacc;
    }
    // ---- E = Tr(C G)/Tr(G), same pair order/signs as the r5 reduce ----
    const int pm[6]={0,0,0,1,1,2}, pn[6]={1,2,3,2,3,3};
    double num = C[0][0].r*G[0] + C[1][1].r*G[1] + C[2][2].r*G[2] + C[3][3].r*G[3];
    for(int p=0;p<6;++p)
      num += 2.0*C[pm[p]][pn[p]].r*G[4+2*p] - 2.0*C[pm[p]][pn[p]].i*G[5+2*p];
    double den = G[0]+G[1]+G[2]+G[3];
    out[0] = (float)(num/den);
  }
}

extern "C" void kernel_launch(void* const* d_in, const int* in_sizes, int n_in,
                              void* d_out, int out_size, void* d_ws, size_t ws_size,
                              hipStream_t stream){
  (void)in_sizes; (void)n_in; (void)out_size; (void)ws_size;
  const float* thetas = (const float*)d_in[0];
  const float* sr = (const float*)d_in[1];
  const float* si = (const float*)d_in[2];
  double* part = (double*)d_ws;

  gramk<<<BLOCKS, THREADS, 0, stream>>>(sr, si, part);
  fink<<<1, 256, 0, stream>>>(thetas, part, (float*)d_out);
}

// Round 7
// 111.709 us; speedup vs baseline: 1.1305x; 1.1305x over previous
//
#include <hip/hip_runtime.h>

#define Q21 (1u<<21)
#define THREADS 512
#define BLOCKS 1024   // 1024*512 threads * 4 quads = 2^21 quads

// ws layout: [0, 1024*16*8) double part[BLOCKS][16] — per-block Gram partials.
//
// Math chain (each step verified on HW, absmax 0 at every stage r1-r6):
//  E = <psi_f|Z_22|psi_f>/||psi||^2 collapses to a 4x4 Hermitian observable C
//  on bits {22,21} (r5), and by linearity (r6):
//     E = Tr(C*G)/Tr(G),  G = sum_v q(v) q(v)^dag,
//     q(v) = (psi[v], psi[v+2^21], psi[v+2^22], psi[v+3*2^21]), v < 2^21.
//  gramk: theta-independent Gram pass (64 MB read, 128 KB write, no atomics).
//  fink: reduce partials + build C + emit E.
//  r7 fix: fink's C-construction used fp64 libm cos/sin (12 calls ~ 60 us
//  single-lane!) and runtime-indexed W/B/C loops (scratch). Replaced with
//  |x|<=0.5 Taylor polys (err <= 1.2e-11) and B-sparse fully-unrolled algebra.
// Pair order p=0..5: (m,n) = (0,1),(0,2),(0,3),(1,2),(1,3),(2,3);
//  G[4+2p]=sum Re(conj(q_m) q_n), G[5+2p]=sum Im(conj(q_m) q_n).

struct cd { double r, i; };
__device__ __forceinline__ cd cmul(cd a, cd b){ return {a.r*b.r - a.i*b.i, a.r*b.i + a.i*b.r}; }
__device__ __forceinline__ cd cjg(cd a){ return {a.r, -a.i}; }
__device__ __forceinline__ cd cadd(cd a, cd b){ return {a.r+b.r, a.i+b.i}; }

// Taylor on |x| <= 0.5 (theta in [0,1), x = theta/2): abs err < 1.2e-11.
__device__ __forceinline__ double psin(double x){
  double x2 = x*x;
  return x*(1.0 + x2*(-1.0/6.0 + x2*(1.0/120.0 + x2*(-1.0/5040.0 + x2*(1.0/362880.0)))));
}
__device__ __forceinline__ double pcos(double x){
  double x2 = x*x;
  return 1.0 + x2*(-0.5 + x2*(1.0/24.0 + x2*(-1.0/720.0 + x2*(1.0/40320.0 + x2*(-1.0/3628800.0)))));
}

// Gram streaming pass: 64 MB read, 128 KB written, no atomics, no init needed.
__global__ __launch_bounds__(THREADS)
void gramk(const float* __restrict__ sr, const float* __restrict__ si,
           double* __restrict__ part){
  int gt = blockIdx.x*THREADS + threadIdx.x;
  int v  = gt<<2;
  float rr[4][4], ii[4][4];
  *(float4*)&rr[0][0] = *(const float4*)(sr+v);
  *(float4*)&rr[1][0] = *(const float4*)(sr+v+Q21);
  *(float4*)&rr[2][0] = *(const float4*)(sr+v+2*Q21);
  *(float4*)&rr[3][0] = *(const float4*)(sr+v+3*Q21);
  *(float4*)&ii[0][0] = *(const float4*)(si+v);
  *(float4*)&ii[1][0] = *(const float4*)(si+v+Q21);
  *(float4*)&ii[2][0] = *(const float4*)(si+v+2*Q21);
  *(float4*)&ii[3][0] = *(const float4*)(si+v+3*Q21);
  float acc[16];
  #pragma unroll
  for(int k=0;k<16;++k) acc[k]=0.f;
  const int pm[6]={0,0,0,1,1,2}, pn[6]={1,2,3,2,3,3};
  #pragma unroll
  for(int e=0;e<4;++e){
    float qr[4]={rr[0][e],rr[1][e],rr[2][e],rr[3][e]};
    float qi[4]={ii[0][e],ii[1][e],ii[2][e],ii[3][e]};
    #pragma unroll
    for(int m=0;m<4;++m) acc[m] += qr[m]*qr[m] + qi[m]*qi[m];
    #pragma unroll
    for(int p=0;p<6;++p){
      int m=pm[p], n=pn[p];
      acc[4+2*p] += qr[m]*qr[n] + qi[m]*qi[n];   // Re(conj(q_m) q_n)
      acc[5+2*p] += qr[m]*qi[n] - qi[m]*qr[n];   // Im(conj(q_m) q_n)
    }
  }
  double d[16];
  #pragma unroll
  for(int k=0;k<16;++k) d[k]=(double)acc[k];
  #pragma unroll
  for(int off=32;off>0;off>>=1){
    #pragma unroll
    for(int k=0;k<16;++k) d[k] += __shfl_down(d[k], off);
  }
  __shared__ double red[8][16];
  int w = threadIdx.x>>6;
  if((threadIdx.x&63)==0){
    #pragma unroll
    for(int k=0;k<16;++k) red[w][k]=d[k];
  }
  __syncthreads();
  if(threadIdx.x<16){
    double s=0;
    #pragma unroll
    for(int i=0;i<8;++i) s += red[i][threadIdx.x];
    part[blockIdx.x*16 + threadIdx.x] = s;
  }
}

// Final: reduce per-block Gram partials, build C (poly-trig fp64, fully
// unrolled / register-resident), output E = Tr(C G)/Tr(G).
__global__ void fink(const float* __restrict__ thetas,
                     const double* __restrict__ part, float* __restrict__ out){
  __shared__ double red[16][17];
  __shared__ double G[16];
  int t = threadIdx.x;                 // 256
  int comp = t&15, grp = t>>4;         // 16 comps x 16 groups
  double s = 0.0;
  #pragma unroll 8
  for(int b=grp; b<BLOCKS; b+=16) s += part[b*16 + comp];
  red[comp][grp] = s;
  __syncthreads();
  if(t<16){
    double g=0;
    #pragma unroll
    for(int i=0;i<16;++i) g += red[t][i];
    G[t]=g;
  }
  __syncthreads();
  if(t==0){
    double a0=0.5*(double)thetas[0], b0=0.5*(double)thetas[1];   // qubit0 L0
    double a1=0.5*(double)thetas[2], b1=0.5*(double)thetas[3];   // qubit1 L0
    double ax=0.5*(double)thetas[46], bx=0.5*(double)thetas[47]; // qubit0 L1
    cd U0[2][2], U1[2][2], V[2][2];
    {
      double ca=pcos(a0), sa=psin(a0), cb=pcos(b0), sb=psin(b0);
      U0[0][0]={ca*cb,-ca*sb}; U0[0][1]={-sa*cb, sa*sb};
      U0[1][0]={sa*cb, sa*sb}; U0[1][1]={ ca*cb, ca*sb};
    }
    {
      double ca=pcos(a1), sa=psin(a1), cb=pcos(b1), sb=psin(b1);
      U1[0][0]={ca*cb,-ca*sb}; U1[0][1]={-sa*cb, sa*sb};
      U1[1][0]={sa*cb, sa*sb}; U1[1][1]={ ca*cb, ca*sb};
    }
    {
      double ca=pcos(ax), sa=psin(ax), cb=pcos(bx), sb=psin(bx);
      V[0][0]={cb*ca, sb*sa}; V[0][1]={-sb*ca,-cb*sa};
      V[1][0]={sb*ca,-cb*sa}; V[1][1]={ cb*ca,-sb*sa};
    }
    // M on bit22: aM = |V00|^2-|V10|^2, O01 = conj(V00)V01 - conj(V10)V11
    double aM = (V[0][0].r*V[0][0].r+V[0][0].i*V[0][0].i)
              - (V[1][0].r*V[1][0].r+V[1][0].i*V[1][0].i);
    cd t1 = cmul(cjg(V[0][0]),V[0][1]), t2 = cmul(cjg(V[1][0]),V[1][1]);
    cd O01 = {t1.r - t2.r, t1.i - t2.i};
    cd O10 = cjg(O01);
    // W = kron(U0,U1), fully unrolled -> registers
    cd W[4][4];
    #pragma unroll
    for(int m=0;m<4;++m)
      #pragma unroll
      for(int n=0;n<4;++n)
        W[m][n] = cmul(U0[m>>1][n>>1], U1[m&1][n&1]);
    // C[m][n] = sum_j sum_k conj(W[j][m]) B[j][k] W[k][n], B sparse:
    //   B = aM*diag(1,1,-1,-1) + O01*(|0><3| + |1><2|) + O10*(|3><0| + |2><1|)
    // num = Tr(C G) via diag + 2Re over the 6 stored upper pairs.
    const int pm[6]={0,0,0,1,1,2}, pn[6]={1,2,3,2,3,3};
    double num = 0.0;
    #pragma unroll
    for(int e=0;e<10;++e){
      int m = (e<4) ? e : pm[e-4];
      int n = (e<4) ? e : pn[e-4];
      cd c = {0,0};
      #pragma unroll
      for(int j=0;j<4;++j){
        double sgn = (j<2) ? aM : -aM;
        cd term = cmul(cjg(W[j][m]), W[j][n]);
        c.r += sgn*term.r; c.i += sgn*term.i;
      }
      c = cadd(c, cmul(O01, cadd(cmul(cjg(W[0][m]),W[3][n]), cmul(cjg(W[1][m]),W[2][n]))));
      c = cadd(c, cmul(O10, cadd(cmul(cjg(W[3][m]),W[0][n]), cmul(cjg(W[2][m]),W[1][n]))));
      if(e<4) num += c.r * G[e];
      else    num += 2.0*c.r*G[4+2*(e-4)] - 2.0*c.i*G[5+2*(e-4)];
    }
    double den = G[0]+G[1]+G[2]+G[3];
    out[0] = (float)(num/den);
  }
}

extern "C" void kernel_launch(void* const* d_in, const int* in_sizes, int n_in,
                              void* d_out, int out_size, void* d_ws, size_t ws_size,
                              hipStream_t stream){
  (void)in_sizes; (void)n_in; (void)out_size; (void)ws_size;
  const float* thetas = (const float*)d_in[0];
  const float* sr = (const float*)d_in[1];
  const float* si = (const float*)d_in[2];
  double* part = (double*)d_ws;

  gramk<<<BLOCKS, THREADS, 0, stream>>>(sr, si, part);
  fink<<<1, 256, 0, stream>>>(thetas, part, (float*)d_out);
}

// Round 8
// 105.607 us; speedup vs baseline: 1.1958x; 1.0578x over previous
//
#include <hip/hip_runtime.h>

#define Q21 (1u<<21)
#define THREADS 512
#define BLOCKS 1024   // 1024*512 threads * 4 quads = 2^21 quads

// ws layout: [0, 1024*16*8) double part[BLOCKS][16] — per-block Gram partials.
//
// Math chain (each step verified on HW, absmax 0 at every stage r1-r7):
//  E = <psi_f|Z_22|psi_f>/||psi||^2 collapses to a 4x4 Hermitian observable C
//  on bits {22,21} (r5), and by linearity (r6):
//     E = Tr(C*G)/Tr(G),  G = sum_v q(v) q(v)^dag,
//     q(v) = (psi[v], psi[v+2^21], psi[v+2^22], psi[v+3*2^21]), v < 2^21.
//  gramk: theta-independent Gram pass (64 MB read, 128 KB write, no atomics).
//  fink: reduce partials + build C (poly-trig fp64, unrolled) + emit E.
//  r8 fix: gramk's tail was a 6-round x16-component fp64 wave shuffle
//  (192 ds_bpermute + 96 v_add_f64 per thread ~ 30-50% of the pass) —
//  replaced with an LDS-transpose reduction (~8 LDS ops/thread).
// Pair order p=0..5: (m,n) = (0,1),(0,2),(0,3),(1,2),(1,3),(2,3);
//  G[4+2p]=sum Re(conj(q_m) q_n), G[5+2p]=sum Im(conj(q_m) q_n).

struct cd { double r, i; };
__device__ __forceinline__ cd cmul(cd a, cd b){ return {a.r*b.r - a.i*b.i, a.r*b.i + a.i*b.r}; }
__device__ __forceinline__ cd cjg(cd a){ return {a.r, -a.i}; }
__device__ __forceinline__ cd cadd(cd a, cd b){ return {a.r+b.r, a.i+b.i}; }

// Taylor on |x| <= 0.5 (theta in [0,1), x = theta/2): abs err < 1.2e-11.
__device__ __forceinline__ double psin(double x){
  double x2 = x*x;
  return x*(1.0 + x2*(-1.0/6.0 + x2*(1.0/120.0 + x2*(-1.0/5040.0 + x2*(1.0/362880.0)))));
}
__device__ __forceinline__ double pcos(double x){
  double x2 = x*x;
  return 1.0 + x2*(-0.5 + x2*(1.0/24.0 + x2*(-1.0/720.0 + x2*(1.0/40320.0 + x2*(-1.0/3628800.0)))));
}

// Gram streaming pass: 64 MB read, 128 KB written, no atomics, no init needed.
__global__ __launch_bounds__(THREADS)
void gramk(const float* __restrict__ sr, const float* __restrict__ si,
           double* __restrict__ part){
  int tid = threadIdx.x;
  int gt = blockIdx.x*THREADS + tid;
  int v  = gt<<2;
  float rr[4][4], ii[4][4];
  *(float4*)&rr[0][0] = *(const float4*)(sr+v);
  *(float4*)&rr[1][0] = *(const float4*)(sr+v+Q21);
  *(float4*)&rr[2][0] = *(const float4*)(sr+v+2*Q21);
  *(float4*)&rr[3][0] = *(const float4*)(sr+v+3*Q21);
  *(float4*)&ii[0][0] = *(const float4*)(si+v);
  *(float4*)&ii[1][0] = *(const float4*)(si+v+Q21);
  *(float4*)&ii[2][0] = *(const float4*)(si+v+2*Q21);
  *(float4*)&ii[3][0] = *(const float4*)(si+v+3*Q21);
  float acc[16];
  #pragma unroll
  for(int k=0;k<16;++k) acc[k]=0.f;
  const int pm[6]={0,0,0,1,1,2}, pn[6]={1,2,3,2,3,3};
  #pragma unroll
  for(int e=0;e<4;++e){
    float qr[4]={rr[0][e],rr[1][e],rr[2][e],rr[3][e]};
    float qi[4]={ii[0][e],ii[1][e],ii[2][e],ii[3][e]};
    #pragma unroll
    for(int m=0;m<4;++m) acc[m] += qr[m]*qr[m] + qi[m]*qi[m];
    #pragma unroll
    for(int p=0;p<6;++p){
      int m=pm[p], n=pn[p];
      acc[4+2*p] += qr[m]*qr[n] + qi[m]*qi[n];   // Re(conj(q_m) q_n)
      acc[5+2*p] += qr[m]*qi[n] - qi[m]*qr[n];   // Im(conj(q_m) q_n)
    }
  }
  // LDS-transpose reduction. Layout: row t, logical chunk c (comps 4c..4c+3)
  // stored at physical chunk pc = c ^ (t&3)  ->  float4-aligned, conflict-lite.
  __shared__ float lds[THREADS*16];          // 32 KB
  __shared__ double red[256];                // [grp][comp] = [ (t>>4)*16 + (t&15) ]
  float4* lds4 = (float4*)lds;
  #pragma unroll
  for(int pc=0; pc<4; ++pc){
    int c = pc ^ (tid&3);
    lds4[(tid<<2)|pc] = make_float4(acc[4*c],acc[4*c+1],acc[4*c+2],acc[4*c+3]);
  }
  __syncthreads();
  if(tid<256){
    int comp = tid&15, grp = tid>>4;         // 16 comps x 16 groups of 32 rows
    double s = 0.0;
    #pragma unroll
    for(int j=0;j<32;++j){
      int r = (grp<<5)|j;
      s += (double)lds[(r<<4) | (comp ^ ((r&3)<<2))];
    }
    red[tid] = s;
  }
  __syncthreads();
  if(tid<16){
    double s=0;
    #pragma unroll
    for(int g=0; g<16; ++g) s += red[g*16 + tid];
    part[blockIdx.x*16 + tid] = s;
  }
}

// Final: reduce per-block Gram partials, build C (poly-trig fp64, fully
// unrolled / register-resident), output E = Tr(C G)/Tr(G).
__global__ void fink(const float* __restrict__ thetas,
                     const double* __restrict__ part, float* __restrict__ out){
  __shared__ double red[16][17];
  __shared__ double G[16];
  int t = threadIdx.x;                 // 256
  int comp = t&15, grp = t>>4;         // 16 comps x 16 groups
  double s = 0.0;
  #pragma unroll 8
  for(int b=grp; b<BLOCKS; b+=16) s += part[b*16 + comp];
  red[comp][grp] = s;
  __syncthreads();
  if(t<16){
    double g=0;
    #pragma unroll
    for(int i=0;i<16;++i) g += red[t][i];
    G[t]=g;
  }
  __syncthreads();
  if(t==0){
    double a0=0.5*(double)thetas[0], b0=0.5*(double)thetas[1];   // qubit0 L0
    double a1=0.5*(double)thetas[2], b1=0.5*(double)thetas[3];   // qubit1 L0
    double ax=0.5*(double)thetas[46], bx=0.5*(double)thetas[47]; // qubit0 L1
    cd U0[2][2], U1[2][2], V[2][2];
    {
      double ca=pcos(a0), sa=psin(a0), cb=pcos(b0), sb=psin(b0);
      U0[0][0]={ca*cb,-ca*sb}; U0[0][1]={-sa*cb, sa*sb};
      U0[1][0]={sa*cb, sa*sb}; U0[1][1]={ ca*cb, ca*sb};
    }
    {
      double ca=pcos(a1), sa=psin(a1), cb=pcos(b1), sb=psin(b1);
      U1[0][0]={ca*cb,-ca*sb}; U1[0][1]={-sa*cb, sa*sb};
      U1[1][0]={sa*cb, sa*sb}; U1[1][1]={ ca*cb, ca*sb};
    }
    {
      double ca=pcos(ax), sa=psin(ax), cb=pcos(bx), sb=psin(bx);
      V[0][0]={cb*ca, sb*sa}; V[0][1]={-sb*ca,-cb*sa};
      V[1][0]={sb*ca,-cb*sa}; V[1][1]={ cb*ca,-sb*sa};
    }
    // M on bit22: aM = |V00|^2-|V10|^2, O01 = conj(V00)V01 - conj(V10)V11
    double aM = (V[0][0].r*V[0][0].r+V[0][0].i*V[0][0].i)
              - (V[1][0].r*V[1][0].r+V[1][0].i*V[1][0].i);
    cd t1 = cmul(cjg(V[0][0]),V[0][1]), t2 = cmul(cjg(V[1][0]),V[1][1]);
    cd O01 = {t1.r - t2.r, t1.i - t2.i};
    cd O10 = cjg(O01);
    cd W[4][4];
    #pragma unroll
    for(int m=0;m<4;++m)
      #pragma unroll
      for(int n=0;n<4;++n)
        W[m][n] = cmul(U0[m>>1][n>>1], U1[m&1][n&1]);
    // C[m][n] from sparse B = aM*diag(1,1,-1,-1) + O01*(|0><3|+|1><2|) + h.c.
    const int pm[6]={0,0,0,1,1,2}, pn[6]={1,2,3,2,3,3};
    double num = 0.0;
    #pragma unroll
    for(int e=0;e<10;++e){
      int m = (e<4) ? e : pm[e-4];
      int n = (e<4) ? e : pn[e-4];
      cd c = {0,0};
      #pragma unroll
      for(int j=0;j<4;++j){
        double sgn = (j<2) ? aM : -aM;
        cd term = cmul(cjg(W[j][m]), W[j][n]);
        c.r += sgn*term.r; c.i += sgn*term.i;
      }
      c = cadd(c, cmul(O01, cadd(cmul(cjg(W[0][m]),W[3][n]), cmul(cjg(W[1][m]),W[2][n]))));
      c = cadd(c, cmul(O10, cadd(cmul(cjg(W[3][m]),W[0][n]), cmul(cjg(W[2][m]),W[1][n]))));
      if(e<4) num += c.r * G[e];
      else    num += 2.0*c.r*G[4+2*(e-4)] - 2.0*c.i*G[5+2*(e-4)];
    }
    double den = G[0]+G[1]+G[2]+G[3];
    out[0] = (float)(num/den);
  }
}

extern "C" void kernel_launch(void* const* d_in, const int* in_sizes, int n_in,
                              void* d_out, int out_size, void* d_ws, size_t ws_size,
                              hipStream_t stream){
  (void)in_sizes; (void)n_in; (void)out_size; (void)ws_size;
  const float* thetas = (const float*)d_in[0];
  const float* sr = (const float*)d_in[1];
  const float* si = (const float*)d_in[2];
  double* part = (double*)d_ws;

  gramk<<<BLOCKS, THREADS, 0, stream>>>(sr, si, part);
  fink<<<1, 256, 0, stream>>>(thetas, part, (float*)d_out);
}